// Round 6
// baseline (270.934 us; speedup 1.0000x reference)
//
#include <hip/hip_runtime.h>
#include <hip/hip_fp16.h>

#define D_MODEL 1024
#define N_HEADS 16
#define HEAD_DIM 64
#define BATCH 2
#define SEQ 2048
#define ROWS (BATCH*SEQ)   // 4096

// K pre-scale: 1/sqrt(d/h)=0.125, folded with log2(e) so softmax uses exp2.
#define K_SCALE 0.18033688011112042f

using h8v = __attribute__((ext_vector_type(8))) _Float16;  // 16x16x32 A/B frag
using h4v = __attribute__((ext_vector_type(4))) _Float16;  // 16x16x16 A/B frag
using f4v = __attribute__((ext_vector_type(4))) float;     // MFMA C/D

__device__ __forceinline__ ushort f2h_u(float x) { return __half_as_ushort(__float2half(x)); }
__device__ __forceinline__ void splith(float x, ushort& h, ushort& l) {
    __half hh_ = __float2half(x);
    h = __half_as_ushort(hh_);
    l = f2h_u(x - __half2float(hh_));
}

// fragment-order index for a [rows][1024] matrix as 16x16x32 MFMA operand:
// chunk ((row>>7)*32 + (k>>5)) of 4096 halves; subtile (row&127)>>4 (512);
// interior ((row&15)*4 + k-octet)*8 + (k&7).
__device__ __forceinline__ size_t fidx(int row, int k) {
    return ((size_t)((row >> 7) * 32 + (k >> 5)) << 12)
         + (size_t)(((row & 127) >> 4) << 9)
         + (size_t)(((row & 15) * 4 + ((k & 31) >> 3)) << 3) + (k & 7);
}

// ---- async global->LDS, 16B/lane --------------------------------------
__device__ __forceinline__ void async_lds16(const ushort* g, ushort* l) {
    __builtin_amdgcn_global_load_lds(
        (const __attribute__((address_space(1))) unsigned int*)g,
        (__attribute__((address_space(3))) unsigned int*)l, 16, 0, 0);
}

// ---------------------------------------------------------------------------
// prep: x -> fp16 hi/lo frag-order; qkv_w -> fp16 hi frag-order;
//       out_w -> fp16 hi/lo frag-order.
// ---------------------------------------------------------------------------
__global__ __launch_bounds__(256)
void prep_kernel(const float* __restrict__ x, const float* __restrict__ qw,
                 const float* __restrict__ ow,
                 ushort* __restrict__ xh, ushort* __restrict__ xl,
                 ushort* __restrict__ qwh,
                 ushort* __restrict__ owh, ushort* __restrict__ owl)
{
    const int b = blockIdx.x, t = threadIdx.x;
    if (b < 4096) {                       // x: 4096x1024, hi+lo
        const int i = b * 256 + t;
        const int row = i >> 8, k4 = (i & 255) * 4;
        const float4 v = ((const float4*)x)[i];
        const size_t o = fidx(row, k4);
        ushort4 h, l;
        splith(v.x, h.x, l.x); splith(v.y, h.y, l.y);
        splith(v.z, h.z, l.z); splith(v.w, h.w, l.w);
        *(ushort4*)&xh[o] = h; *(ushort4*)&xl[o] = l;
    } else if (b < 7168) {                // qkv_w: 3072x1024, hi only
        const int i = (b - 4096) * 256 + t;
        const int row = i >> 8, k4 = (i & 255) * 4;
        const float4 v = ((const float4*)qw)[i];
        ushort4 h;
        h.x = f2h_u(v.x); h.y = f2h_u(v.y); h.z = f2h_u(v.z); h.w = f2h_u(v.w);
        *(ushort4*)&qwh[fidx(row, k4)] = h;
    } else {                              // out_w: 1024x1024, hi+lo
        const int i = (b - 7168) * 256 + t;
        const int row = i >> 8, k4 = (i & 255) * 4;
        const float4 v = ((const float4*)ow)[i];
        const size_t o = fidx(row, k4);
        ushort4 h, l;
        splith(v.x, h.x, l.x); splith(v.y, h.y, l.y);
        splith(v.z, h.z, l.z); splith(v.w, h.w, l.w);
        *(ushort4*)&owh[o] = h; *(ushort4*)&owl[o] = l;
    }
}

// ---------------------------------------------------------------------------
// Fused QKV GEMM, single-barrier prefetch pipeline. 128x128 tile, BK=32.
// nb<16 (Q/K): transposed mfma, ushort4 stores into Q/K frag layouts
//              (K pre-scaled). nb>=16 (V): standard mfma, ushort4 stores
//              into V^T layout (d-major, PV A-operand order).
// A = x hi/lo (2 mfma), W = qkv_w hi only.
// ---------------------------------------------------------------------------
__global__ __launch_bounds__(256)
void gemm_qkv(const ushort* __restrict__ Af, const ushort* __restrict__ Alf,
              const ushort* __restrict__ Wf, const float* __restrict__ bias,
              ushort* __restrict__ Qh, ushort* __restrict__ Kh,
              ushort* __restrict__ Vt)
{
    __shared__ ushort sA[2][8192];   // [0,4096) hi | [4096,8192) lo
    __shared__ ushort sW[2][4096];
    const int t = threadIdx.x, lane = t & 63, wv = t >> 6;
    const int tx = lane & 15, g = lane >> 4;
    const int nb = blockIdx.x, mb = blockIdx.y;
    const int at0 = (wv >> 1) * 4, wt0 = (wv & 1) * 4;
    const int fo = (tx * 4 + g) * 8;

    f4v acc[4][4];
#pragma unroll
    for (int i = 0; i < 4; i++)
#pragma unroll
        for (int j = 0; j < 4; j++)
#pragma unroll
            for (int e = 0; e < 4; e++) acc[i][j][e] = 0.f;

    {   // prologue: stage kt=0
        const size_t ao = ((size_t)(mb * 32)) << 12;
        const size_t wo = ((size_t)(nb * 32)) << 12;
#pragma unroll
        for (int c = 0; c < 2; c++) {
            const int o = (t + c * 256) * 8;
            async_lds16(Af + ao + o, &sA[0][o]);
            async_lds16(Alf + ao + o, &sA[0][4096 + o]);
            async_lds16(Wf + wo + o, &sW[0][o]);
        }
    }

    for (int kt = 0; kt < 32; kt++) {
        const int p = kt & 1;
        __syncthreads();   // stage(kt) drained; compute(kt-1) reads done
        if (kt < 31) {
            const size_t ao = ((size_t)(mb * 32 + kt + 1)) << 12;
            const size_t wo = ((size_t)(nb * 32 + kt + 1)) << 12;
#pragma unroll
            for (int c = 0; c < 2; c++) {
                const int o = (t + c * 256) * 8;
                async_lds16(Af + ao + o, &sA[p ^ 1][o]);
                async_lds16(Alf + ao + o, &sA[p ^ 1][4096 + o]);
                async_lds16(Wf + wo + o, &sW[p ^ 1][o]);
            }
        }
        h8v ah[4], al[4], wh[4];
#pragma unroll
        for (int i = 0; i < 4; i++) {
            ah[i] = *(const h8v*)&sA[p][(at0 + i) * 512 + fo];
            al[i] = *(const h8v*)&sA[p][4096 + (at0 + i) * 512 + fo];
            wh[i] = *(const h8v*)&sW[p][(wt0 + i) * 512 + fo];
        }
        if (nb < 16) {       // transposed: acc[wi][ai]
#pragma unroll
            for (int i = 0; i < 4; i++)
#pragma unroll
                for (int j = 0; j < 4; j++) {
                    acc[i][j] = __builtin_amdgcn_mfma_f32_16x16x32_f16(wh[i], ah[j], acc[i][j], 0, 0, 0);
                    acc[i][j] = __builtin_amdgcn_mfma_f32_16x16x32_f16(wh[i], al[j], acc[i][j], 0, 0, 0);
                }
        } else {             // standard: acc[ai][wi]
#pragma unroll
            for (int i = 0; i < 4; i++)
#pragma unroll
                for (int j = 0; j < 4; j++) {
                    acc[i][j] = __builtin_amdgcn_mfma_f32_16x16x32_f16(ah[i], wh[j], acc[i][j], 0, 0, 0);
                    acc[i][j] = __builtin_amdgcn_mfma_f32_16x16x32_f16(al[i], wh[j], acc[i][j], 0, 0, 0);
                }
        }
    }

    if (nb < 16) {
        const int part = nb >> 3;                    // 0=Q, 1=K
        ushort* dst = part ? Kh : Qh;
        const float scale = part ? K_SCALE : 1.0f;
#pragma unroll
        for (int wi = 0; wi < 4; wi++) {
            const int gf0 = nb * 128 + (wv & 1) * 64 + wi * 16 + g * 4;
            const float4 bv = *(const float4*)&bias[gf0];
            const int hh = (gf0 & 1023) >> 6;
            const int dd = gf0 & 63;
#pragma unroll
            for (int ai = 0; ai < 4; ai++) {
                const int s = mb * 128 + (wv >> 1) * 64 + ai * 16 + tx;
                const int bb = s >> 11, srel = s & 2047;
                const size_t idx = (size_t)(bb * N_HEADS + hh) * 131072
                    + (size_t)(srel >> 4) * 1024 + (size_t)(dd >> 5) * 512
                    + ((srel & 15) * 4 + ((dd & 31) >> 3)) * 8 + (dd & 7);
                ushort4 h4;
                h4.x = f2h_u((acc[wi][ai][0] + bv.x) * scale);
                h4.y = f2h_u((acc[wi][ai][1] + bv.y) * scale);
                h4.z = f2h_u((acc[wi][ai][2] + bv.z) * scale);
                h4.w = f2h_u((acc[wi][ai][3] + bv.w) * scale);
                *(ushort4*)&dst[idx] = h4;
            }
        }
    } else {
        // V^T layout: head chunk (j>>6)*4096; tile (((j>>4)&3)*4 + d>>4)*256;
        // interior ((d&15)*4 + ((j&15)>>2))*4 + (j&3)
#pragma unroll
        for (int wi = 0; wi < 4; wi++) {
            const int gf = nb * 128 + (wv & 1) * 64 + wi * 16 + tx;
            const float bv = bias[gf];
            const int hh = (gf & 1023) >> 6;
            const int dl = gf & 63;
#pragma unroll
            for (int ai = 0; ai < 4; ai++) {
                const int jt0 = mb * 128 + (wv >> 1) * 64 + ai * 16 + g * 4;
                const int bb = jt0 >> 11, jr = jt0 & 2047;
                const size_t idx = (size_t)(bb * N_HEADS + hh) * 131072
                    + (size_t)(jr >> 6) * 4096
                    + (size_t)((((jr >> 4) & 3) * 4) + (dl >> 4)) * 256
                    + ((dl & 15) * 4 + ((jr & 15) >> 2)) * 4;
                ushort4 h4;
                h4.x = f2h_u(acc[ai][wi][0] + bv);
                h4.y = f2h_u(acc[ai][wi][1] + bv);
                h4.z = f2h_u(acc[ai][wi][2] + bv);
                h4.w = f2h_u(acc[ai][wi][3] + bv);
                *(ushort4*)&Vt[idx] = h4;
            }
        }
    }
}

// ---------------------------------------------------------------------------
// MFMA flash attention (quirk: scores = K.Q^T, K pre-scaled; K rows act as
// queries). A=Q, B=K -> C[j][i]: per-lane p registers are exactly the
// B-operand fragment of v_mfma_f32_16x16x16_f16 -> PV straight from
// registers, no P LDS round-trip. O^T = V^T x P^T (V = A operand).
// Single-barrier prefetch: K's LDS region becomes the 2nd Q/V buffer.
// LDS 32KB. XCD swizzle for L2 locality.
// ---------------------------------------------------------------------------
__global__ __launch_bounds__(256)
void attn_mfma(const ushort* __restrict__ Kf, const ushort* __restrict__ Qf,
               const ushort* __restrict__ Vf,
               ushort* __restrict__ Oh, ushort* __restrict__ Ol)
{
    __shared__ ushort lds[16384];    // R0: K then buf; R1: buf
    ushort* R0 = lds;
    ushort* R1 = lds + 8192;

    const int t = threadIdx.x, lane = t & 63, wv = t >> 6;
    const int tx = lane & 15, g = lane >> 4;
    const int lin = blockIdx.x;
    const int xcd = lin & 7, ix = lin >> 3;
    const int bh = xcd * 4 + (ix >> 4);
    const int it = ix & 15;
    const int b = bh >> 4, h = bh & 15;
    const int i0 = it * 128;
    const size_t hb = (size_t)bh * 131072;

    {   // stage K tile -> R0; (Q,V) chunk jt=0 -> R1
        const size_t kb = hb + (size_t)it * 8192;
#pragma unroll
        for (int c = 0; c < 4; c++) {
            const int o = (t + c * 256) * 8;
            async_lds16(Kf + kb + o, R0 + o);
        }
#pragma unroll
        for (int c = 0; c < 2; c++) {
            const int o = (t + c * 256) * 8;
            async_lds16(Qf + hb + o, R1 + o);
            async_lds16(Vf + hb + o, R1 + 4096 + o);
        }
    }
    __syncthreads();

    const int fo = (tx * 4 + g) * 8;
    h8v kf[2][2];
#pragma unroll
    for (int is = 0; is < 2; is++)
#pragma unroll
        for (int kk = 0; kk < 2; kk++)
            kf[is][kk] = *(const h8v*)&R0[((wv * 2 + is) * 2 + kk) * 512 + fo];

    f4v O[2][4];
    float l_acc[2] = {0.f, 0.f};
#pragma unroll
    for (int is = 0; is < 2; is++)
#pragma unroll
        for (int ht = 0; ht < 4; ht++)
#pragma unroll
            for (int e = 0; e < 4; e++) O[is][ht][e] = 0.f;

    for (int jt = 0; jt < SEQ / 64; jt++) {
        ushort* buf = (jt & 1) ? R0 : R1;
        ushort* nxt = (jt & 1) ? R1 : R0;
        __syncthreads();   // buf staged (vmcnt drained); prev reads of nxt done
        if (jt < SEQ / 64 - 1) {
            const size_t off = hb + (size_t)(jt + 1) * 4096;
#pragma unroll
            for (int c = 0; c < 2; c++) {
                const int o = (t + c * 256) * 8;
                async_lds16(Qf + off + o, nxt + o);
                async_lds16(Vf + off + o, nxt + 4096 + o);
            }
        }
        const ushort* sQ = buf;
        const ushort* sV = buf + 4096;

        // ---- S^T = Q.K^T: C[j = jn*16+g*4+r][i = is*16+tx] ----
        f4v sc[2][4];
#pragma unroll
        for (int is = 0; is < 2; is++)
#pragma unroll
            for (int jn = 0; jn < 4; jn++)
#pragma unroll
                for (int e = 0; e < 4; e++) sc[is][jn][e] = 0.f;
#pragma unroll
        for (int kk = 0; kk < 2; kk++)
#pragma unroll
            for (int jn = 0; jn < 4; jn++) {
                const h8v qf = *(const h8v*)&sQ[(jn * 2 + kk) * 512 + fo];
#pragma unroll
                for (int is = 0; is < 2; is++)
                    sc[is][jn] = __builtin_amdgcn_mfma_f32_16x16x32_f16(qf, kf[is][kk], sc[is][jn], 0, 0, 0);
            }

        // ---- fixed-origin exp2 -> P^T B-frags in registers ----
        h4v ph[2][4];
#pragma unroll
        for (int is = 0; is < 2; is++)
#pragma unroll
            for (int jn = 0; jn < 4; jn++) {
                const float p0 = __builtin_amdgcn_exp2f(sc[is][jn][0]);
                const float p1 = __builtin_amdgcn_exp2f(sc[is][jn][1]);
                const float p2 = __builtin_amdgcn_exp2f(sc[is][jn][2]);
                const float p3 = __builtin_amdgcn_exp2f(sc[is][jn][3]);
                l_acc[is] += (p0 + p1) + (p2 + p3);
                h4v pv;
                pv[0] = (_Float16)p0; pv[1] = (_Float16)p1;
                pv[2] = (_Float16)p2; pv[3] = (_Float16)p3;
                ph[is][jn] = pv;
            }

        // ---- O^T += V^T x P^T (K=16 mfma, V = A operand) ----
#pragma unroll
        for (int jc = 0; jc < 4; jc++)
#pragma unroll
            for (int ht = 0; ht < 4; ht++) {
                const h4v vf = *(const h4v*)&sV[(jc * 4 + ht) * 256 + (tx * 4 + g) * 4];
#pragma unroll
                for (int is = 0; is < 2; is++)
                    O[is][ht] = __builtin_amdgcn_mfma_f32_16x16x16f16(vf, ph[is][jc], O[is][ht], 0, 0, 0);
            }
    }

    // ---- epilogue: l = sum over g-groups; O^T/l -> Oh/Ol frag-order ----
#pragma unroll
    for (int is = 0; is < 2; is++) {
        float l = l_acc[is];
        l += __shfl_xor(l, 16);
        l += __shfl_xor(l, 32);
        const float inv = 1.0f / l;
        const int row = b * SEQ + i0 + wv * 32 + is * 16 + tx;   // token i
#pragma unroll
        for (int ht = 0; ht < 4; ht++) {
            const int k0 = h * 64 + ht * 16 + g * 4;
            const size_t o = fidx(row, k0);
            ushort4 hv, lv;
            float v;
            v = O[is][ht][0] * inv; splith(v, hv.x, lv.x);
            v = O[is][ht][1] * inv; splith(v, hv.y, lv.y);
            v = O[is][ht][2] * inv; splith(v, hv.z, lv.z);
            v = O[is][ht][3] * inv; splith(v, hv.w, lv.w);
            *(ushort4*)&Oh[o] = hv;
            *(ushort4*)&Ol[o] = lv;
        }
    }
}

// ---------------------------------------------------------------------------
// Out-proj GEMM: A = attn-out hi/lo, W = out_w hi/lo, 3-mfma emulation,
// transposed epilogue, fp32 float4 out. Single-barrier prefetch.
// ---------------------------------------------------------------------------
__global__ __launch_bounds__(256)
void gemm_out(const ushort* __restrict__ Af, const ushort* __restrict__ Alf,
              const ushort* __restrict__ Wf, const ushort* __restrict__ Wlf,
              const float* __restrict__ bias, float* __restrict__ out)
{
    __shared__ ushort sA[2][8192], sW[2][8192];
    const int t = threadIdx.x, lane = t & 63, wv = t >> 6;
    const int tx = lane & 15, g = lane >> 4;
    const int nb = blockIdx.x, mb = blockIdx.y;
    const int at0 = (wv >> 1) * 4, wt0 = (wv & 1) * 4;
    const int fo = (tx * 4 + g) * 8;

    f4v acc[4][4];
#pragma unroll
    for (int i = 0; i < 4; i++)
#pragma unroll
        for (int j = 0; j < 4; j++)
#pragma unroll
            for (int e = 0; e < 4; e++) acc[i][j][e] = 0.f;

    {
        const size_t ao = ((size_t)(mb * 32)) << 12;
        const size_t wo = ((size_t)(nb * 32)) << 12;
#pragma unroll
        for (int c = 0; c < 2; c++) {
            const int o = (t + c * 256) * 8;
            async_lds16(Af + ao + o, &sA[0][o]);
            async_lds16(Alf + ao + o, &sA[0][4096 + o]);
            async_lds16(Wf + wo + o, &sW[0][o]);
            async_lds16(Wlf + wo + o, &sW[0][4096 + o]);
        }
    }

    for (int kt = 0; kt < 32; kt++) {
        const int p = kt & 1;
        __syncthreads();
        if (kt < 31) {
            const size_t ao = ((size_t)(mb * 32 + kt + 1)) << 12;
            const size_t wo = ((size_t)(nb * 32 + kt + 1)) << 12;
#pragma unroll
            for (int c = 0; c < 2; c++) {
                const int o = (t + c * 256) * 8;
                async_lds16(Af + ao + o, &sA[p ^ 1][o]);
                async_lds16(Alf + ao + o, &sA[p ^ 1][4096 + o]);
                async_lds16(Wf + wo + o, &sW[p ^ 1][o]);
                async_lds16(Wlf + wo + o, &sW[p ^ 1][4096 + o]);
            }
        }
        h8v ah[4], al[4], wh[4], wl[4];
#pragma unroll
        for (int i = 0; i < 4; i++) {
            ah[i] = *(const h8v*)&sA[p][(at0 + i) * 512 + fo];
            al[i] = *(const h8v*)&sA[p][4096 + (at0 + i) * 512 + fo];
            wh[i] = *(const h8v*)&sW[p][(wt0 + i) * 512 + fo];
            wl[i] = *(const h8v*)&sW[p][4096 + (wt0 + i) * 512 + fo];
        }
#pragma unroll
        for (int i = 0; i < 4; i++)
#pragma unroll
            for (int j = 0; j < 4; j++) {
                acc[i][j] = __builtin_amdgcn_mfma_f32_16x16x32_f16(wh[i], ah[j], acc[i][j], 0, 0, 0);
                acc[i][j] = __builtin_amdgcn_mfma_f32_16x16x32_f16(wh[i], al[j], acc[i][j], 0, 0, 0);
                acc[i][j] = __builtin_amdgcn_mfma_f32_16x16x32_f16(wl[i], ah[j], acc[i][j], 0, 0, 0);
            }
    }

#pragma unroll
    for (int wi = 0; wi < 4; wi++) {
        const int gf0 = nb * 128 + (wv & 1) * 64 + wi * 16 + g * 4;
        const float4 bv = *(const float4*)&bias[gf0];
#pragma unroll
        for (int ai = 0; ai < 4; ai++) {
            const int tok = mb * 128 + (wv >> 1) * 64 + ai * 16 + tx;
            float4 o;
            o.x = acc[wi][ai][0] + bv.x;
            o.y = acc[wi][ai][1] + bv.y;
            o.z = acc[wi][ai][2] + bv.z;
            o.w = acc[wi][ai][3] + bv.w;
            *(float4*)&out[(size_t)tok * D_MODEL + gf0] = o;
        }
    }
}

// ---------------------------------------------------------------------------
// ws plan (44 MB):
//   xh 8MB | xl 8MB  (reused as Oh/Ol by attn)  | Qh | Kh | Vt (8MB each)
//   qwh 6MB | owh 2MB | owl 2MB
// ---------------------------------------------------------------------------
extern "C" void kernel_launch(void* const* d_in, const int* in_sizes, int n_in,
                              void* d_out, int out_size, void* d_ws, size_t ws_size,
                              hipStream_t stream) {
    const float* x     = (const float*)d_in[0];
    const float* qkv_w = (const float*)d_in[1];
    const float* qkv_b = (const float*)d_in[2];
    const float* out_w = (const float*)d_in[3];
    const float* out_b = (const float*)d_in[4];
    float* out = (float*)d_out;

    const size_t FB = (size_t)ROWS * D_MODEL;        // 4,194,304 halves
    const size_t MM = (size_t)D_MODEL * D_MODEL;
    ushort* u   = (ushort*)d_ws;
    ushort* xh  = u;             // -> Oh after attn
    ushort* xl  = u + FB;        // -> Ol
    ushort* Qh  = u + 2 * FB;
    ushort* Kh  = u + 3 * FB;
    ushort* Vt  = u + 4 * FB;
    ushort* qwh = u + 5 * FB;
    ushort* owh = u + 5 * FB + 3 * MM;
    ushort* owl = owh + MM;

    prep_kernel<<<8192, 256, 0, stream>>>(x, qkv_w, out_w, xh, xl, qwh, owh, owl);
    gemm_qkv<<<dim3(24, ROWS / 128), 256, 0, stream>>>(
        xh, xl, qwh, qkv_b, Qh, Kh, Vt);
    attn_mfma<<<dim3(512), 256, 0, stream>>>(Kh, Qh, Vt, xh, xl);
    gemm_out<<<dim3(8, ROWS / 128), 256, 0, stream>>>(
        xh, xl, owh, owl, out_b, out);
}

// Round 7
// 256.926 us; speedup vs baseline: 1.0545x; 1.0545x over previous
//
#include <hip/hip_runtime.h>
#include <hip/hip_fp16.h>

#define D_MODEL 1024
#define N_HEADS 16
#define HEAD_DIM 64
#define BATCH 2
#define SEQ 2048
#define ROWS (BATCH*SEQ)   // 4096

// K pre-scale: 1/sqrt(d/h)=0.125, folded with log2(e) so softmax uses exp2.
#define K_SCALE 0.18033688011112042f

using h8v = __attribute__((ext_vector_type(8))) _Float16;  // 16x16x32 A/B frag
using h4v = __attribute__((ext_vector_type(4))) _Float16;  // 16x16x16 A/B frag
using f4v = __attribute__((ext_vector_type(4))) float;     // MFMA C/D

__device__ __forceinline__ ushort f2h_u(float x) { return __half_as_ushort(__float2half(x)); }
__device__ __forceinline__ void splith(float x, ushort& h, ushort& l) {
    __half hh_ = __float2half(x);
    h = __half_as_ushort(hh_);
    l = f2h_u(x - __half2float(hh_));
}

// fragment-order index for a [rows][1024] matrix as 16x16x32 MFMA operand:
// chunk ((row>>7)*32 + (k>>5)) of 4096 halves; subtile (row&127)>>4 (512);
// interior ((row&15)*4 + k-octet)*8 + (k&7).
__device__ __forceinline__ size_t fidx(int row, int k) {
    return ((size_t)((row >> 7) * 32 + (k >> 5)) << 12)
         + (size_t)(((row & 127) >> 4) << 9)
         + (size_t)(((row & 15) * 4 + ((k & 31) >> 3)) << 3) + (k & 7);
}

// ---- async global->LDS, 16B/lane --------------------------------------
__device__ __forceinline__ void async_lds16(const ushort* g, ushort* l) {
    __builtin_amdgcn_global_load_lds(
        (const __attribute__((address_space(1))) unsigned int*)g,
        (__attribute__((address_space(3))) unsigned int*)l, 16, 0, 0);
}

// ---------------------------------------------------------------------------
// prep: x -> fp16 hi frag-order; qkv_w -> fp16 hi frag-order;
//       out_w -> fp16 hi/lo frag-order.
// ---------------------------------------------------------------------------
__global__ __launch_bounds__(256)
void prep_kernel(const float* __restrict__ x, const float* __restrict__ qw,
                 const float* __restrict__ ow,
                 ushort* __restrict__ xh, ushort* __restrict__ qwh,
                 ushort* __restrict__ owh, ushort* __restrict__ owl)
{
    const int b = blockIdx.x, t = threadIdx.x;
    if (b < 4096) {                       // x: 4096x1024, hi only
        const int i = b * 256 + t;
        const int row = i >> 8, k4 = (i & 255) * 4;
        const float4 v = ((const float4*)x)[i];
        ushort4 h;
        h.x = f2h_u(v.x); h.y = f2h_u(v.y); h.z = f2h_u(v.z); h.w = f2h_u(v.w);
        *(ushort4*)&xh[fidx(row, k4)] = h;
    } else if (b < 7168) {                // qkv_w: 3072x1024, hi only
        const int i = (b - 4096) * 256 + t;
        const int row = i >> 8, k4 = (i & 255) * 4;
        const float4 v = ((const float4*)qw)[i];
        ushort4 h;
        h.x = f2h_u(v.x); h.y = f2h_u(v.y); h.z = f2h_u(v.z); h.w = f2h_u(v.w);
        *(ushort4*)&qwh[fidx(row, k4)] = h;
    } else {                              // out_w: 1024x1024, hi+lo
        const int i = (b - 7168) * 256 + t;
        const int row = i >> 8, k4 = (i & 255) * 4;
        const float4 v = ((const float4*)ow)[i];
        const size_t o = fidx(row, k4);
        ushort4 h, l;
        splith(v.x, h.x, l.x); splith(v.y, h.y, l.y);
        splith(v.z, h.z, l.z); splith(v.w, h.w, l.w);
        *(ushort4*)&owh[o] = h; *(ushort4*)&owl[o] = l;
    }
}

// ---------------------------------------------------------------------------
// Fused QKV GEMM, fp16 hi x hi (1 mfma per tile-pair = m97 shape).
// 128x128 tile, BK=32, single-barrier 1-ahead prefetch, LDS 32KB.
// XCD swizzle: xcd owns mb in {xcd*4..+3} -> per-XCD A = 1MB (L2-resident),
// A fetched from HBM exactly once.
// nb<16 (Q/K): transposed mfma -> Q/K frag layouts (K pre-scaled).
// nb>=16 (V): standard mfma -> V^T layout (d-major, PV A-operand order).
// ---------------------------------------------------------------------------
__global__ __launch_bounds__(256)
void gemm_qkv(const ushort* __restrict__ Af, const ushort* __restrict__ Wf,
              const float* __restrict__ bias,
              ushort* __restrict__ Qh, ushort* __restrict__ Kh,
              ushort* __restrict__ Vt)
{
    __shared__ ushort sA[2][4096], sW[2][4096];
    const int t = threadIdx.x, lane = t & 63, wv = t >> 6;
    const int tx = lane & 15, g = lane >> 4;
    const int lin = blockIdx.x;
    const int xcd = lin & 7, r = lin >> 3;       // r 0..95
    const int mb = xcd * 4 + (r & 3);            // 0..31
    const int nb = r >> 2;                       // 0..23
    const int at0 = (wv >> 1) * 4, wt0 = (wv & 1) * 4;
    const int fo = (tx * 4 + g) * 8;

    f4v acc[4][4];
#pragma unroll
    for (int i = 0; i < 4; i++)
#pragma unroll
        for (int j = 0; j < 4; j++)
#pragma unroll
            for (int e = 0; e < 4; e++) acc[i][j][e] = 0.f;

    {   // prologue: stage kt=0
        const size_t ao = ((size_t)(mb * 32)) << 12;
        const size_t wo = ((size_t)(nb * 32)) << 12;
#pragma unroll
        for (int c = 0; c < 2; c++) {
            const int o = (t + c * 256) * 8;
            async_lds16(Af + ao + o, &sA[0][o]);
            async_lds16(Wf + wo + o, &sW[0][o]);
        }
    }

    for (int kt = 0; kt < 32; kt++) {
        const int p = kt & 1;
        __syncthreads();   // stage(kt) drained; compute(kt-1) reads done
        if (kt < 31) {
            const size_t ao = ((size_t)(mb * 32 + kt + 1)) << 12;
            const size_t wo = ((size_t)(nb * 32 + kt + 1)) << 12;
#pragma unroll
            for (int c = 0; c < 2; c++) {
                const int o = (t + c * 256) * 8;
                async_lds16(Af + ao + o, &sA[p ^ 1][o]);
                async_lds16(Wf + wo + o, &sW[p ^ 1][o]);
            }
        }
        h8v ah[4], wh[4];
#pragma unroll
        for (int i = 0; i < 4; i++) {
            ah[i] = *(const h8v*)&sA[p][(at0 + i) * 512 + fo];
            wh[i] = *(const h8v*)&sW[p][(wt0 + i) * 512 + fo];
        }
        if (nb < 16) {       // transposed: acc[wi][ai]
#pragma unroll
            for (int i = 0; i < 4; i++)
#pragma unroll
                for (int j = 0; j < 4; j++)
                    acc[i][j] = __builtin_amdgcn_mfma_f32_16x16x32_f16(wh[i], ah[j], acc[i][j], 0, 0, 0);
        } else {             // standard: acc[ai][wi]
#pragma unroll
            for (int i = 0; i < 4; i++)
#pragma unroll
                for (int j = 0; j < 4; j++)
                    acc[i][j] = __builtin_amdgcn_mfma_f32_16x16x32_f16(ah[i], wh[j], acc[i][j], 0, 0, 0);
        }
    }

    if (nb < 16) {
        const int part = nb >> 3;                    // 0=Q, 1=K
        ushort* dst = part ? Kh : Qh;
        const float scale = part ? K_SCALE : 1.0f;
#pragma unroll
        for (int wi = 0; wi < 4; wi++) {
            const int gf0 = nb * 128 + (wv & 1) * 64 + wi * 16 + g * 4;
            const float4 bv = *(const float4*)&bias[gf0];
            const int hh = (gf0 & 1023) >> 6;
            const int dd = gf0 & 63;
#pragma unroll
            for (int ai = 0; ai < 4; ai++) {
                const int s = mb * 128 + (wv >> 1) * 64 + ai * 16 + tx;
                const int bb = s >> 11, srel = s & 2047;
                const size_t idx = (size_t)(bb * N_HEADS + hh) * 131072
                    + (size_t)(srel >> 4) * 1024 + (size_t)(dd >> 5) * 512
                    + ((srel & 15) * 4 + ((dd & 31) >> 3)) * 8 + (dd & 7);
                ushort4 h4;
                h4.x = f2h_u((acc[wi][ai][0] + bv.x) * scale);
                h4.y = f2h_u((acc[wi][ai][1] + bv.y) * scale);
                h4.z = f2h_u((acc[wi][ai][2] + bv.z) * scale);
                h4.w = f2h_u((acc[wi][ai][3] + bv.w) * scale);
                *(ushort4*)&dst[idx] = h4;
            }
        }
    } else {
        // V^T layout: head chunk (j>>6)*4096; tile (((j>>4)&3)*4 + d>>4)*256;
        // interior ((d&15)*4 + ((j&15)>>2))*4 + (j&3)
#pragma unroll
        for (int wi = 0; wi < 4; wi++) {
            const int gf = nb * 128 + (wv & 1) * 64 + wi * 16 + tx;
            const float bv = bias[gf];
            const int hh = (gf & 1023) >> 6;
            const int dl = gf & 63;
#pragma unroll
            for (int ai = 0; ai < 4; ai++) {
                const int jt0 = mb * 128 + (wv >> 1) * 64 + ai * 16 + g * 4;
                const int bb = jt0 >> 11, jr = jt0 & 2047;
                const size_t idx = (size_t)(bb * N_HEADS + hh) * 131072
                    + (size_t)(jr >> 6) * 4096
                    + (size_t)((((jr >> 4) & 3) * 4) + (dl >> 4)) * 256
                    + ((dl & 15) * 4 + ((jr & 15) >> 2)) * 4;
                ushort4 h4;
                h4.x = f2h_u(acc[ai][wi][0] + bv);
                h4.y = f2h_u(acc[ai][wi][1] + bv);
                h4.z = f2h_u(acc[ai][wi][2] + bv);
                h4.w = f2h_u(acc[ai][wi][3] + bv);
                *(ushort4*)&Vt[idx] = h4;
            }
        }
    }
}

// ---------------------------------------------------------------------------
// MFMA flash attention (quirk: scores = K.Q^T, K pre-scaled; K rows act as
// queries). A=Q, B=K -> C[j][i]: per-lane p registers are exactly the
// B-operand fragment of v_mfma_f32_16x16x16_f16 -> PV straight from
// registers, no P LDS round-trip. O^T = V^T x P^T (V = A operand).
// Single-barrier prefetch: K's LDS region becomes the 2nd Q/V buffer.
// LDS 32KB. XCD swizzle for L2 locality.
// ---------------------------------------------------------------------------
__global__ __launch_bounds__(256)
void attn_mfma(const ushort* __restrict__ Kf, const ushort* __restrict__ Qf,
               const ushort* __restrict__ Vf,
               ushort* __restrict__ Oh, ushort* __restrict__ Ol)
{
    __shared__ ushort lds[16384];    // R0: K then buf; R1: buf
    ushort* R0 = lds;
    ushort* R1 = lds + 8192;

    const int t = threadIdx.x, lane = t & 63, wv = t >> 6;
    const int tx = lane & 15, g = lane >> 4;
    const int lin = blockIdx.x;
    const int xcd = lin & 7, ix = lin >> 3;
    const int bh = xcd * 4 + (ix >> 4);
    const int it = ix & 15;
    const int b = bh >> 4, h = bh & 15;
    const int i0 = it * 128;
    const size_t hb = (size_t)bh * 131072;

    {   // stage K tile -> R0; (Q,V) chunk jt=0 -> R1
        const size_t kb = hb + (size_t)it * 8192;
#pragma unroll
        for (int c = 0; c < 4; c++) {
            const int o = (t + c * 256) * 8;
            async_lds16(Kf + kb + o, R0 + o);
        }
#pragma unroll
        for (int c = 0; c < 2; c++) {
            const int o = (t + c * 256) * 8;
            async_lds16(Qf + hb + o, R1 + o);
            async_lds16(Vf + hb + o, R1 + 4096 + o);
        }
    }
    __syncthreads();

    const int fo = (tx * 4 + g) * 8;
    h8v kf[2][2];
#pragma unroll
    for (int is = 0; is < 2; is++)
#pragma unroll
        for (int kk = 0; kk < 2; kk++)
            kf[is][kk] = *(const h8v*)&R0[((wv * 2 + is) * 2 + kk) * 512 + fo];

    f4v O[2][4];
    float l_acc[2] = {0.f, 0.f};
#pragma unroll
    for (int is = 0; is < 2; is++)
#pragma unroll
        for (int ht = 0; ht < 4; ht++)
#pragma unroll
            for (int e = 0; e < 4; e++) O[is][ht][e] = 0.f;

    for (int jt = 0; jt < SEQ / 64; jt++) {
        ushort* buf = (jt & 1) ? R0 : R1;
        ushort* nxt = (jt & 1) ? R1 : R0;
        __syncthreads();   // buf staged (vmcnt drained); prev reads of nxt done
        if (jt < SEQ / 64 - 1) {
            const size_t off = hb + (size_t)(jt + 1) * 4096;
#pragma unroll
            for (int c = 0; c < 2; c++) {
                const int o = (t + c * 256) * 8;
                async_lds16(Qf + off + o, nxt + o);
                async_lds16(Vf + off + o, nxt + 4096 + o);
            }
        }
        const ushort* sQ = buf;
        const ushort* sV = buf + 4096;

        // ---- S^T = Q.K^T: C[j = jn*16+g*4+r][i = is*16+tx] ----
        f4v sc[2][4];
#pragma unroll
        for (int is = 0; is < 2; is++)
#pragma unroll
            for (int jn = 0; jn < 4; jn++)
#pragma unroll
                for (int e = 0; e < 4; e++) sc[is][jn][e] = 0.f;
#pragma unroll
        for (int kk = 0; kk < 2; kk++)
#pragma unroll
            for (int jn = 0; jn < 4; jn++) {
                const h8v qf = *(const h8v*)&sQ[(jn * 2 + kk) * 512 + fo];
#pragma unroll
                for (int is = 0; is < 2; is++)
                    sc[is][jn] = __builtin_amdgcn_mfma_f32_16x16x32_f16(qf, kf[is][kk], sc[is][jn], 0, 0, 0);
            }

        // ---- fixed-origin exp2 -> P^T B-frags in registers ----
        h4v ph[2][4];
#pragma unroll
        for (int is = 0; is < 2; is++)
#pragma unroll
            for (int jn = 0; jn < 4; jn++) {
                const float p0 = __builtin_amdgcn_exp2f(sc[is][jn][0]);
                const float p1 = __builtin_amdgcn_exp2f(sc[is][jn][1]);
                const float p2 = __builtin_amdgcn_exp2f(sc[is][jn][2]);
                const float p3 = __builtin_amdgcn_exp2f(sc[is][jn][3]);
                l_acc[is] += (p0 + p1) + (p2 + p3);
                h4v pv;
                pv[0] = (_Float16)p0; pv[1] = (_Float16)p1;
                pv[2] = (_Float16)p2; pv[3] = (_Float16)p3;
                ph[is][jn] = pv;
            }

        // ---- O^T += V^T x P^T (K=16 mfma, V = A operand) ----
#pragma unroll
        for (int jc = 0; jc < 4; jc++)
#pragma unroll
            for (int ht = 0; ht < 4; ht++) {
                const h4v vf = *(const h4v*)&sV[(jc * 4 + ht) * 256 + (tx * 4 + g) * 4];
#pragma unroll
                for (int is = 0; is < 2; is++)
                    O[is][ht] = __builtin_amdgcn_mfma_f32_16x16x16f16(vf, ph[is][jc], O[is][ht], 0, 0, 0);
            }
    }

    // ---- epilogue: l = sum over g-groups; O^T/l -> Oh/Ol frag-order ----
#pragma unroll
    for (int is = 0; is < 2; is++) {
        float l = l_acc[is];
        l += __shfl_xor(l, 16);
        l += __shfl_xor(l, 32);
        const float inv = 1.0f / l;
        const int row = b * SEQ + i0 + wv * 32 + is * 16 + tx;   // token i
#pragma unroll
        for (int ht = 0; ht < 4; ht++) {
            const int k0 = h * 64 + ht * 16 + g * 4;
            const size_t o = fidx(row, k0);
            ushort4 hv, lv;
            float v;
            v = O[is][ht][0] * inv; splith(v, hv.x, lv.x);
            v = O[is][ht][1] * inv; splith(v, hv.y, lv.y);
            v = O[is][ht][2] * inv; splith(v, hv.z, lv.z);
            v = O[is][ht][3] * inv; splith(v, hv.w, lv.w);
            *(ushort4*)&Oh[o] = hv;
            *(ushort4*)&Ol[o] = lv;
        }
    }
}

// ---------------------------------------------------------------------------
// Out-proj GEMM: A = attn-out hi/lo, W = out_w hi/lo, 3-mfma emulation,
// transposed epilogue, fp32 float4 out. Single-barrier prefetch.
// XCD swizzle: each XCD owns one nb -> W-tile (0.5MB) L2-resident.
// ---------------------------------------------------------------------------
__global__ __launch_bounds__(256)
void gemm_out(const ushort* __restrict__ Af, const ushort* __restrict__ Alf,
              const ushort* __restrict__ Wf, const ushort* __restrict__ Wlf,
              const float* __restrict__ bias, float* __restrict__ out)
{
    __shared__ ushort sA[2][8192], sW[2][8192];
    const int t = threadIdx.x, lane = t & 63, wv = t >> 6;
    const int tx = lane & 15, g = lane >> 4;
    const int lin = blockIdx.x;
    const int nb = lin & 7, mb = lin >> 3;
    const int at0 = (wv >> 1) * 4, wt0 = (wv & 1) * 4;
    const int fo = (tx * 4 + g) * 8;

    f4v acc[4][4];
#pragma unroll
    for (int i = 0; i < 4; i++)
#pragma unroll
        for (int j = 0; j < 4; j++)
#pragma unroll
            for (int e = 0; e < 4; e++) acc[i][j][e] = 0.f;

    {
        const size_t ao = ((size_t)(mb * 32)) << 12;
        const size_t wo = ((size_t)(nb * 32)) << 12;
#pragma unroll
        for (int c = 0; c < 2; c++) {
            const int o = (t + c * 256) * 8;
            async_lds16(Af + ao + o, &sA[0][o]);
            async_lds16(Alf + ao + o, &sA[0][4096 + o]);
            async_lds16(Wf + wo + o, &sW[0][o]);
            async_lds16(Wlf + wo + o, &sW[0][4096 + o]);
        }
    }

    for (int kt = 0; kt < 32; kt++) {
        const int p = kt & 1;
        __syncthreads();
        if (kt < 31) {
            const size_t ao = ((size_t)(mb * 32 + kt + 1)) << 12;
            const size_t wo = ((size_t)(nb * 32 + kt + 1)) << 12;
#pragma unroll
            for (int c = 0; c < 2; c++) {
                const int o = (t + c * 256) * 8;
                async_lds16(Af + ao + o, &sA[p ^ 1][o]);
                async_lds16(Alf + ao + o, &sA[p ^ 1][4096 + o]);
                async_lds16(Wf + wo + o, &sW[p ^ 1][o]);
                async_lds16(Wlf + wo + o, &sW[p ^ 1][4096 + o]);
            }
        }
        h8v ah[4], al[4], wh[4], wl[4];
#pragma unroll
        for (int i = 0; i < 4; i++) {
            ah[i] = *(const h8v*)&sA[p][(at0 + i) * 512 + fo];
            al[i] = *(const h8v*)&sA[p][4096 + (at0 + i) * 512 + fo];
            wh[i] = *(const h8v*)&sW[p][(wt0 + i) * 512 + fo];
            wl[i] = *(const h8v*)&sW[p][4096 + (wt0 + i) * 512 + fo];
        }
#pragma unroll
        for (int i = 0; i < 4; i++)
#pragma unroll
            for (int j = 0; j < 4; j++) {
                acc[i][j] = __builtin_amdgcn_mfma_f32_16x16x32_f16(wh[i], ah[j], acc[i][j], 0, 0, 0);
                acc[i][j] = __builtin_amdgcn_mfma_f32_16x16x32_f16(wh[i], al[j], acc[i][j], 0, 0, 0);
                acc[i][j] = __builtin_amdgcn_mfma_f32_16x16x32_f16(wl[i], ah[j], acc[i][j], 0, 0, 0);
            }
    }

#pragma unroll
    for (int wi = 0; wi < 4; wi++) {
        const int gf0 = nb * 128 + (wv & 1) * 64 + wi * 16 + g * 4;
        const float4 bv = *(const float4*)&bias[gf0];
#pragma unroll
        for (int ai = 0; ai < 4; ai++) {
            const int tok = mb * 128 + (wv >> 1) * 64 + ai * 16 + tx;
            float4 o;
            o.x = acc[wi][ai][0] + bv.x;
            o.y = acc[wi][ai][1] + bv.y;
            o.z = acc[wi][ai][2] + bv.z;
            o.w = acc[wi][ai][3] + bv.w;
            *(float4*)&out[(size_t)tok * D_MODEL + gf0] = o;
        }
    }
}

// ---------------------------------------------------------------------------
// ws plan (44 MB):
//   xh 8MB (-> Oh after attn) | Ol 8MB | Qh | Kh | Vt (8MB each)
//   qwh 6MB | owh 2MB | owl 2MB
// ---------------------------------------------------------------------------
extern "C" void kernel_launch(void* const* d_in, const int* in_sizes, int n_in,
                              void* d_out, int out_size, void* d_ws, size_t ws_size,
                              hipStream_t stream) {
    const float* x     = (const float*)d_in[0];
    const float* qkv_w = (const float*)d_in[1];
    const float* qkv_b = (const float*)d_in[2];
    const float* out_w = (const float*)d_in[3];
    const float* out_b = (const float*)d_in[4];
    float* out = (float*)d_out;

    const size_t FB = (size_t)ROWS * D_MODEL;        // 4,194,304 halves
    const size_t MM = (size_t)D_MODEL * D_MODEL;
    ushort* u   = (ushort*)d_ws;
    ushort* xh  = u;             // -> Oh after attn
    ushort* Ol  = u + FB;
    ushort* Qh  = u + 2 * FB;
    ushort* Kh  = u + 3 * FB;
    ushort* Vt  = u + 4 * FB;
    ushort* qwh = u + 5 * FB;
    ushort* owh = u + 5 * FB + 3 * MM;
    ushort* owl = owh + MM;

    prep_kernel<<<8192, 256, 0, stream>>>(x, qkv_w, out_w, xh, qwh, owh, owl);
    gemm_qkv<<<768, 256, 0, stream>>>(xh, qwh, qkv_b, Qh, Kh, Vt);
    attn_mfma<<<512, 256, 0, stream>>>(Kh, Qh, Vt, xh, Ol);
    gemm_out<<<256, 256, 0, stream>>>(xh, Ol, owh, owl, out_b, out);
}